// Round 1
// baseline (1051.523 us; speedup 1.0000x reference)
//
#include <hip/hip_runtime.h>
#include <math.h>

#define TSTEPS 300
#define NBATCH 256
#define IN_K   578
#define KPAD   612          // 612 mod 32 = 4 -> bank-group +1 per row; 16B-aligned rows
#define NH1    20
#define NH2    10
#define TM     64           // rows per block in kernel A
#define NROWS  (TSTEPS * NBATCH)   // 76800

// ---------------------------------------------------------------------------
// Kernel P: pad W1 [20][578] -> W1p [20][612], zero tail (lets the k-loop run
// uniformly over [0,612) with zero contributions from the pad region).
__global__ void pad_w1(const float* __restrict__ W1, float* __restrict__ W1p) {
    int idx = blockIdx.x * 256 + threadIdx.x;
    if (idx >= NH1 * KPAD) return;
    int h = idx / KPAD;
    int k = idx - h * KPAD;
    W1p[idx] = (k < IN_K) ? W1[h * IN_K + k] : 0.f;
}

// ---------------------------------------------------------------------------
// Kernel A: cur1[b][t][h] = b1[h] + sum_k xs[t,b,k] * W1[h,k]
// xs = nearest-downsampled x (even rows/cols of each 34x34 plane).
// Block: 1024 threads, 64 rows staged in LDS. 16 waves = 4 h-groups x 4 k-quarters.
__global__ __launch_bounds__(1024, 4) void snn_layer1(
    const float* __restrict__ x, const float* __restrict__ W1p,
    const float* __restrict__ b1, float* __restrict__ cur1)
{
    __shared__ float xs[TM * KPAD];   // 156,672 B
    const int tid  = threadIdx.x;
    const int row0 = blockIdx.x * TM;  // global row = t*256 + b

    // ---- stage: per row 34 segments (c,i), each = 8 float4 + 1 float -------
    // segment = even source row 2i of channel c; we load its first 132 bytes
    // (the span containing the 17 needed even columns) as contiguous chunks.
    for (int slot = tid; slot < TM * 306; slot += 1024) {
        int r   = slot / 306;
        int rem = slot - r * 306;
        int s   = rem / 9;
        int q   = rem - s * 9;
        int c   = (s >= 17) ? 1 : 0;
        int i   = s - 17 * c;
        const float* seg = x + (row0 + r) * 2312 + c * 1156 + i * 68;
        float* dst = xs + r * KPAD + c * 289 + i * 17;
        if (q < 8) {
            float4 v = *reinterpret_cast<const float4*>(seg + 4 * q);
            dst[2 * q]     = v.x;   // col 4q   -> j = 2q
            dst[2 * q + 1] = v.z;   // col 4q+2 -> j = 2q+1
        } else {
            dst[16] = seg[32];      // col 32 -> j = 16
        }
    }
    // zero-pad [578, 612) per row
    for (int id = tid; id < TM * 34; id += 1024) {
        int r = id / 34;
        int z = id - r * 34;
        xs[r * KPAD + IN_K + z] = 0.f;
    }
    __syncthreads();

    // ---- compute: lane = row, wave-uniform (h-group, k-quarter) ------------
    const int wave = tid >> 6;
    const int lane = tid & 63;
    const int hb = __builtin_amdgcn_readfirstlane((wave & 3) * 5);
    const int ks = __builtin_amdgcn_readfirstlane(wave >> 2);
    const int kbeg = ks * 152;
    const int kend = (ks == 3) ? KPAD : (kbeg + 152);

    const float* lr    = xs + lane * KPAD;
    const float* wbase = W1p + hb * KPAD;
    float a0 = 0.f, a1 = 0.f, a2 = 0.f, a3 = 0.f, a4 = 0.f;
    for (int k = kbeg; k < kend; k += 4) {
        float4 xv  = *reinterpret_cast<const float4*>(lr + k);
        float4 wq0 = *reinterpret_cast<const float4*>(wbase + k);
        float4 wq1 = *reinterpret_cast<const float4*>(wbase + KPAD + k);
        float4 wq2 = *reinterpret_cast<const float4*>(wbase + 2 * KPAD + k);
        float4 wq3 = *reinterpret_cast<const float4*>(wbase + 3 * KPAD + k);
        float4 wq4 = *reinterpret_cast<const float4*>(wbase + 4 * KPAD + k);
        a0 = fmaf(xv.x, wq0.x, a0); a0 = fmaf(xv.y, wq0.y, a0);
        a0 = fmaf(xv.z, wq0.z, a0); a0 = fmaf(xv.w, wq0.w, a0);
        a1 = fmaf(xv.x, wq1.x, a1); a1 = fmaf(xv.y, wq1.y, a1);
        a1 = fmaf(xv.z, wq1.z, a1); a1 = fmaf(xv.w, wq1.w, a1);
        a2 = fmaf(xv.x, wq2.x, a2); a2 = fmaf(xv.y, wq2.y, a2);
        a2 = fmaf(xv.z, wq2.z, a2); a2 = fmaf(xv.w, wq2.w, a2);
        a3 = fmaf(xv.x, wq3.x, a3); a3 = fmaf(xv.y, wq3.y, a3);
        a3 = fmaf(xv.z, wq3.z, a3); a3 = fmaf(xv.w, wq3.w, a3);
        a4 = fmaf(xv.x, wq4.x, a4); a4 = fmaf(xv.y, wq4.y, a4);
        a4 = fmaf(xv.z, wq4.z, a4); a4 = fmaf(xv.w, wq4.w, a4);
    }
    __syncthreads();

    // ---- cross-k-quarter reduction via LDS (alias xs: compute is done) ----
    float* part = xs;                         // [4][64][20] = 20,480 B
    int pb = (ks * TM + lane) * NH1 + hb;
    part[pb]     = a0;
    part[pb + 1] = a1;
    part[pb + 2] = a2;
    part[pb + 3] = a3;
    part[pb + 4] = a4;
    __syncthreads();

    for (int o = tid; o < TM * NH1; o += 1024) {
        int r = o / NH1;
        int h = o - r * NH1;
        float v = ((part[r * NH1 + h] + part[(TM + r) * NH1 + h])
                   + part[(2 * TM + r) * NH1 + h]) + part[(3 * TM + r) * NH1 + h];
        v += b1[h];
        int row = row0 + r;          // = t*256 + b
        int tt  = row >> 8;
        int bb  = row & 255;
        cur1[(bb * TSTEPS + tt) * NH1 + h] = v;
    }
}

// ---------------------------------------------------------------------------
// Kernel B: per-batch sequential LIF recurrence + spike count + softmax.
// One wave per batch. Lanes 0..19 = layer-1 units; lanes 0..9 = layer-2 units.
__global__ __launch_bounds__(64, 1) void snn_layer2(
    const float* __restrict__ cur1, const float* __restrict__ W2,
    const float* __restrict__ b2,   const float* __restrict__ beta1,
    const float* __restrict__ th1,  const float* __restrict__ beta2,
    const float* __restrict__ th2,  float* __restrict__ out)
{
    __shared__ float4 cbuf4[TSTEPS * NH1 / 4];   // 24 KB: this batch's cur1
    const int b    = blockIdx.x;
    const int lane = threadIdx.x;

    const float4* src4 = reinterpret_cast<const float4*>(cur1 + b * (TSTEPS * NH1));
    for (int v = lane; v < TSTEPS * NH1 / 4; v += 64) cbuf4[v] = src4[v];
    __syncthreads();
    const float* cbuf = reinterpret_cast<const float*>(cbuf4);

    float bc1 = 0.f, thv1 = 0.f;
    if (lane < NH1) {
        bc1  = fminf(fmaxf(beta1[lane], 0.f), 1.f);
        thv1 = th1[lane];
    }
    float4 q0 = {0,0,0,0}, q1 = {0,0,0,0}, q2 = {0,0,0,0}, q3 = {0,0,0,0}, q4 = {0,0,0,0};
    float b2v = 0.f, bc2 = 0.f, thv2 = 0.f;
    if (lane < NH2) {
        const float4* wr = reinterpret_cast<const float4*>(W2 + lane * NH1);
        q0 = wr[0]; q1 = wr[1]; q2 = wr[2]; q3 = wr[3]; q4 = wr[4];
        b2v  = b2[lane];
        bc2  = fminf(fmaxf(beta2[lane], 0.f), 1.f);
        thv2 = th2[lane];
    }

    float mem1 = 0.f, mem2 = 0.f, cnt = 0.f;
    #pragma unroll 4
    for (int t = 0; t < TSTEPS; ++t) {
        float cur = (lane < NH1) ? cbuf[t * NH1 + lane] : 0.f;
        // reset uses pre-update membrane (matches reference; unfused rounding)
        float rst1 = (__fsub_rn(mem1, thv1) > 0.f) ? thv1 : 0.f;
        mem1 = __fsub_rn(__fadd_rn(__fmul_rn(bc1, mem1), cur), rst1);
        bool spk = (lane < NH1) && (__fsub_rn(mem1, thv1) > 0.f);
        unsigned long long mk = __ballot(spk);

        float s0 = 0.f, s1 = 0.f, s2 = 0.f, s3 = 0.f;
        if (mk & (1ull << 0))  s0 += q0.x;
        if (mk & (1ull << 1))  s1 += q0.y;
        if (mk & (1ull << 2))  s2 += q0.z;
        if (mk & (1ull << 3))  s3 += q0.w;
        if (mk & (1ull << 4))  s0 += q1.x;
        if (mk & (1ull << 5))  s1 += q1.y;
        if (mk & (1ull << 6))  s2 += q1.z;
        if (mk & (1ull << 7))  s3 += q1.w;
        if (mk & (1ull << 8))  s0 += q2.x;
        if (mk & (1ull << 9))  s1 += q2.y;
        if (mk & (1ull << 10)) s2 += q2.z;
        if (mk & (1ull << 11)) s3 += q2.w;
        if (mk & (1ull << 12)) s0 += q3.x;
        if (mk & (1ull << 13)) s1 += q3.y;
        if (mk & (1ull << 14)) s2 += q3.z;
        if (mk & (1ull << 15)) s3 += q3.w;
        if (mk & (1ull << 16)) s0 += q4.x;
        if (mk & (1ull << 17)) s1 += q4.y;
        if (mk & (1ull << 18)) s2 += q4.z;
        if (mk & (1ull << 19)) s3 += q4.w;
        float dot  = __fadd_rn(__fadd_rn(s0, s1), __fadd_rn(s2, s3));
        float cur2 = __fadd_rn(dot, b2v);

        float rst2 = (__fsub_rn(mem2, thv2) > 0.f) ? thv2 : 0.f;
        mem2 = __fsub_rn(__fadd_rn(__fmul_rn(bc2, mem2), cur2), rst2);
        if (__fsub_rn(mem2, thv2) > 0.f) cnt += 1.f;
    }

    // softmax over lanes 0..9 (lanes 10..15 padded with -inf / 0)
    float v = (lane < NH2) ? cnt : -INFINITY;
    v = fmaxf(v, __shfl_xor(v, 1));
    v = fmaxf(v, __shfl_xor(v, 2));
    v = fmaxf(v, __shfl_xor(v, 4));
    v = fmaxf(v, __shfl_xor(v, 8));
    float e = (lane < NH2) ? expf(cnt - v) : 0.f;
    float se = e;
    se += __shfl_xor(se, 1);
    se += __shfl_xor(se, 2);
    se += __shfl_xor(se, 4);
    se += __shfl_xor(se, 8);
    if (lane < NH2) out[b * NH2 + lane] = e / se;
}

// ---------------------------------------------------------------------------
extern "C" void kernel_launch(void* const* d_in, const int* in_sizes, int n_in,
                              void* d_out, int out_size, void* d_ws, size_t ws_size,
                              hipStream_t stream) {
    const float* x     = (const float*)d_in[0];
    const float* W1    = (const float*)d_in[1];
    const float* b1    = (const float*)d_in[2];
    const float* W2    = (const float*)d_in[3];
    const float* b2    = (const float*)d_in[4];
    const float* beta1 = (const float*)d_in[5];
    const float* th1   = (const float*)d_in[6];
    const float* beta2 = (const float*)d_in[7];
    const float* th2   = (const float*)d_in[8];
    float* out = (float*)d_out;

    float* W1p  = (float*)d_ws;                         // 20*612*4 = 48,960 B
    float* cur1 = (float*)((char*)d_ws + 49152);        // [256][300][20] = 6,144,000 B

    pad_w1<<<(NH1 * KPAD + 255) / 256, 256, 0, stream>>>(W1, W1p);
    snn_layer1<<<NROWS / TM, 1024, 0, stream>>>(x, W1p, b1, cur1);
    snn_layer2<<<NBATCH, 64, 0, stream>>>(cur1, W2, b2, beta1, th1, beta2, th2, out);
}